// Round 5
// baseline (1263.693 us; speedup 1.0000x reference)
//
#include <hip/hip_runtime.h>
#include <stdint.h>

#define EMB 1024
#define LROW 40   // staging LDS pitch (u16): 32 data + 8 pad -> 2-way max on frag reads
#define EROW 136  // epilogue LDS pitch (u16): 128 data + 8 pad -> bank shift 4/row

typedef unsigned short u16;
typedef __attribute__((ext_vector_type(8))) unsigned short u16x8;
typedef __attribute__((ext_vector_type(8))) __bf16 bf16x8;
typedef __attribute__((ext_vector_type(4))) float f32x4;

__device__ __forceinline__ u16 f2bf(float f) {
  union { float f; uint32_t u; } x; x.f = f;
  uint32_t u = x.u;
  u += 0x7fff + ((u >> 16) & 1u);   // round-to-nearest-even
  return (u16)(u >> 16);
}
__device__ __forceinline__ float bf2f(u16 u) {
  union { uint32_t u; float f; } x; x.u = ((uint32_t)u) << 16;
  return x.f;
}

// Load 8 contiguous elements (f32 -> cvt to bf16, or raw bf16) as u16x8 bits.
template<int F32>
__device__ __forceinline__ u16x8 ld8(const void* p, size_t off) {
  if (F32) {
    const float4* f = (const float4*)((const float*)p + off);
    const float4 lo = f[0], hi = f[1];
    u16x8 r;
    r[0] = f2bf(lo.x); r[1] = f2bf(lo.y); r[2] = f2bf(lo.z); r[3] = f2bf(lo.w);
    r[4] = f2bf(hi.x); r[5] = f2bf(hi.y); r[6] = f2bf(hi.z); r[7] = f2bf(hi.w);
    return r;
  }
  return *(const u16x8*)((const u16*)p + off);
}

// One 128x128 C tile of C = X @ W^T + bias. W/bias always f32 external.
// X: f32 (XF32=1) or bf16. C: f32 (CF32=1, scalar stores = full 64B lines) or
// bf16 (CF32=0, LDS-coalesced epilogue: u16x8 stores = full lines, no RMW).
// smem: [0, 128*LROW) = Al, [128*LROW, 2*128*LROW) = Bl;
// CF32=0 additionally overlays epilogue tile [0, 128*EROW) after the K-loop.
template<int XF32, int CF32>
__device__ __forceinline__ void gemm_core(
    const void* __restrict__ X, const float* __restrict__ W,
    const float* __restrict__ Bias, void* __restrict__ C,
    int bm, int bn, int N, int K, u16* smem)
{
  u16* Al = smem;
  u16* Bl = smem + 128 * LROW;

  const int tid  = threadIdx.x;
  const int lane = tid & 63;
  const int w    = tid >> 6;
  const int wm = w >> 1, wn = w & 1;
  const int r16 = lane & 15, quad = lane >> 4;

  // 512 8-elem segments per 128x32 tile; thread covers seg tid and tid+256.
  const int s0 = tid, s1 = tid + 256;
  const int r0 = s0 >> 2, k0o = (s0 & 3) * 8;
  const int r1 = s1 >> 2, k1o = (s1 & 3) * 8;
  const int l0 = r0 * LROW + k0o;
  const int l1 = r1 * LROW + k1o;

  const size_t xo0 = (size_t)(bm + r0) * K + k0o;
  const size_t xo1 = (size_t)(bm + r1) * K + k1o;
  const size_t wo0 = (size_t)(bn + r0) * K + k0o;
  const size_t wo1 = (size_t)(bn + r1) * K + k1o;

  f32x4 acc[4][4];
#pragma unroll
  for (int i = 0; i < 4; i++)
#pragma unroll
    for (int j = 0; j < 4; j++)
      acc[i][j] = f32x4{0.f, 0.f, 0.f, 0.f};

  // prefetch k=0 slice
  u16x8 xa = ld8<XF32>(X, xo0);
  u16x8 xb = ld8<XF32>(X, xo1);
  u16x8 wa = ld8<1>(W, wo0);
  u16x8 wb = ld8<1>(W, wo1);

  for (int k0 = 0; k0 < K; k0 += 32) {
    *(u16x8*)&Al[l0] = xa;
    *(u16x8*)&Al[l1] = xb;
    *(u16x8*)&Bl[l0] = wa;
    *(u16x8*)&Bl[l1] = wb;
    __syncthreads();

    // prefetch next K-slice (wraps on last iter -- always valid addrs)
    const int kn = (k0 + 32 < K) ? (k0 + 32) : 0;
    xa = ld8<XF32>(X, xo0 + kn);
    xb = ld8<XF32>(X, xo1 + kn);
    wa = ld8<1>(W, wo0 + kn);
    wb = ld8<1>(W, wo1 + kn);

    bf16x8 a[4], b[4];
#pragma unroll
    for (int t = 0; t < 4; t++)
      a[t] = *(const bf16x8*)&Al[(wm * 64 + t * 16 + r16) * LROW + quad * 8];
#pragma unroll
    for (int t = 0; t < 4; t++)
      b[t] = *(const bf16x8*)&Bl[(wn * 64 + t * 16 + r16) * LROW + quad * 8];

#pragma unroll
    for (int tm = 0; tm < 4; tm++)
#pragma unroll
      for (int tn = 0; tn < 4; tn++)
        acc[tm][tn] = __builtin_amdgcn_mfma_f32_16x16x32_bf16(a[tm], b[tn], acc[tm][tn], 0, 0, 0);
    __syncthreads();
  }

  // C/D layout: col = lane&15, row = quad*4 + reg  (verified m89/m91)
  if (CF32) {
    // f32 scalar stores: 16 lanes x 4B = 64B full lines per quad-row -> no RMW.
#pragma unroll
    for (int tn = 0; tn < 4; tn++) {
      const int col = bn + wn * 64 + tn * 16 + r16;
      const float bias = Bias[col];
#pragma unroll
      for (int tm = 0; tm < 4; tm++) {
        const int row0 = bm + wm * 64 + tm * 16 + quad * 4;
#pragma unroll
        for (int r = 0; r < 4; r++)
          ((float*)C)[(size_t)(row0 + r) * N + col] = acc[tm][tn][r] + bias;
      }
    }
  } else {
    // bf16: round-trip through LDS so each wave stores 4 x 256B contiguous row
    // segments (u16x8/lane) -> every 64B line written exactly once.
#pragma unroll
    for (int tn = 0; tn < 4; tn++) {
      const int col = wn * 64 + tn * 16 + r16;
      const float bias = Bias[bn + col];
#pragma unroll
      for (int tm = 0; tm < 4; tm++) {
        const int row0 = wm * 64 + tm * 16 + quad * 4;
#pragma unroll
        for (int r = 0; r < 4; r++)
          smem[(row0 + r) * EROW + col] = f2bf(acc[tm][tn][r] + bias);
      }
    }
    __syncthreads();
#pragma unroll
    for (int p = 0; p < 8; p++) {
      const int idx = p * 256 + tid;          // 2048 u16x8 chunks in the tile
      const int row = idx >> 4;
      const int c8  = (idx & 15) * 8;
      const u16x8 val = *(const u16x8*)&smem[row * EROW + c8];
      *(u16x8*)&((u16*)C)[(size_t)(bm + row) * N + bn + c8] = val;
    }
  }
}

// Fused Q/K/V projections: blockIdx.z selects operand set (1536 blocks).
__global__ __launch_bounds__(256, 4) void qkv_gemm_kernel(
    const float* Vx, const float* Kx, const float* Qx,
    const float* Wv, const float* bv, const float* Wk, const float* bk,
    const float* Wq, const float* bq,
    u16* cv, u16* ck, u16* cq, int N, int K)
{
  __shared__ __attribute__((aligned(16))) u16 smem[128 * EROW];  // 34.8 KB: staging + epilogue overlay
  const float* X; const float* W; const float* B; u16* C;
  switch (blockIdx.z) {
    case 0:  X = Vx; W = Wv; B = bv; C = cv; break;
    case 1:  X = Kx; W = Wk; B = bk; C = ck; break;
    default: X = Qx; W = Wq; B = bq; C = cq; break;
  }
  gemm_core<1, 0>(X, W, B, C, blockIdx.y * 128, blockIdx.x * 128, N, K, smem);
}

__global__ __launch_bounds__(256, 4) void out_gemm_kernel(
    const u16* X, const float* W, const float* B, float* C, int N, int K)
{
  __shared__ __attribute__((aligned(16))) u16 smem[2 * 128 * LROW];  // 20 KB staging only
  gemm_core<0, 1>(X, W, B, C, blockIdx.y * 128, blockIdx.x * 128, N, K, smem);
}

// Per-token head-mixing attention: S = (Q Kt^T)/8 over 16 heads, softmax over
// g, O = S V. One wave per token; all operands bf16 internal.
// O aliases Q (each wave reads its own Q before writing its own O).
__global__ __launch_bounds__(256, 2) void attn_heads_kernel(
    const u16* Q, const u16* Km, const u16* V, u16* O)
{
  __shared__ __attribute__((aligned(16))) u16 P[4][16 * LROW];   // P zero-padded to K=32
  __shared__ __attribute__((aligned(16))) u16 VT[4][64 * LROW];  // V^T [d][g], g-cols 16..31 zeroed

  const int tid = threadIdx.x, lane = tid & 63, w = tid >> 6;
  const int r16 = lane & 15, quad = lane >> 4;
  const size_t base = ((size_t)blockIdx.x * 4 + w) * EMB;

  // Q rows (head-major, d-contiguous) are exactly A-layout; K rows are B-layout.
  const bf16x8 aq0 = *(const bf16x8*)&Q[base + r16 * 64 + quad * 8];
  const bf16x8 aq1 = *(const bf16x8*)&Q[base + r16 * 64 + 32 + quad * 8];
  const bf16x8 bk0 = *(const bf16x8*)&Km[base + r16 * 64 + quad * 8];
  const bf16x8 bk1 = *(const bf16x8*)&Km[base + r16 * 64 + 32 + quad * 8];

  // Stage this wave's V (2 KB) transposed into VT[w].
  const u16x8 v0 = *(const u16x8*)&V[base + lane * 16];
  const u16x8 v1 = *(const u16x8*)&V[base + lane * 16 + 8];
  const u16x8 z8 = {0, 0, 0, 0, 0, 0, 0, 0};
  *(u16x8*)&VT[w][lane * LROW + 16] = z8;   // zero g-cols 16..31 (row d = lane)
  *(u16x8*)&VT[w][lane * LROW + 24] = z8;
  const int g = lane >> 2, dbase = (lane & 3) * 16;
#pragma unroll
  for (int i = 0; i < 8; i++) {
    VT[w][(dbase + i) * LROW + g]     = v0[i];
    VT[w][(dbase + 8 + i) * LROW + g] = v1[i];
  }

  f32x4 s = f32x4{0.f, 0.f, 0.f, 0.f};
  s = __builtin_amdgcn_mfma_f32_16x16x32_bf16(aq0, bk0, s, 0, 0, 0);
  s = __builtin_amdgcn_mfma_f32_16x16x32_bf16(aq1, bk1, s, 0, 0, 0);
  // s[r] = S[h=quad*4+r][g=lane&15]

  float p[4];
#pragma unroll
  for (int r = 0; r < 4; r++) {
    float v = s[r] * 0.125f;             // 1/sqrt(64)
    float m = v;
#pragma unroll
    for (int d = 8; d; d >>= 1) m = fmaxf(m, __shfl_xor(m, d, 16));
    float e = __expf(v - m);
    float sum = e;
#pragma unroll
    for (int d = 8; d; d >>= 1) sum += __shfl_xor(sum, d, 16);
    p[r] = e / sum;
  }

  // P (C-layout) -> LDS [h][g], zero-padded to K=32
#pragma unroll
  for (int r = 0; r < 4; r++) {
    P[w][(quad * 4 + r) * LROW + r16]      = f2bf(p[r]);
    P[w][(quad * 4 + r) * LROW + 16 + r16] = 0;
  }
  __syncthreads();

  const bf16x8 pa = *(const bf16x8*)&P[w][r16 * LROW + quad * 8];  // A-frag of P

#pragma unroll
  for (int c = 0; c < 4; c++) {     // 4 chunks of 16 output dims
    const bf16x8 bv = *(const bf16x8*)&VT[w][(c * 16 + r16) * LROW + quad * 8];
    f32x4 o = f32x4{0.f, 0.f, 0.f, 0.f};
    o = __builtin_amdgcn_mfma_f32_16x16x32_bf16(pa, bv, o, 0, 0, 0);
#pragma unroll
    for (int r = 0; r < 4; r++)
      O[base + (size_t)(quad * 4 + r) * 64 + c * 16 + r16] = f2bf(o[r]);
  }
}

extern "C" void kernel_launch(void* const* d_in, const int* in_sizes, int n_in,
                              void* d_out, int out_size, void* d_ws, size_t ws_size,
                              hipStream_t stream)
{
  const float* values = (const float*)d_in[0];
  const float* keys   = (const float*)d_in[1];
  const float* query  = (const float*)d_in[2];
  const float* Wv = (const float*)d_in[3];
  const float* bv = (const float*)d_in[4];
  const float* Wk = (const float*)d_in[5];
  const float* bk = (const float*)d_in[6];
  const float* Wq = (const float*)d_in[7];
  const float* bq = (const float*)d_in[8];
  const float* Wo = (const float*)d_in[9];
  const float* bo = (const float*)d_in[10];

  const int M = in_sizes[0] / EMB;   // 8192 tokens
  const int N = EMB, K = EMB;

  // ws: q | k (bf16, 16 MB each). v lives as bf16 in d_out (32 MB f32 buffer;
  // dead before out-GEMM overwrites it). Attention output aliases q.
  u16* q = (u16*)d_ws;
  u16* k = q + (size_t)M * EMB;
  u16* v = (u16*)d_out;
  u16* ao = q;

  dim3 blk(256, 1, 1);
  hipLaunchKernelGGL(qkv_gemm_kernel, dim3(N / 128, M / 128, 3), blk, 0, stream,
                     values, keys, query, Wv, bv, Wk, bk, Wq, bq, v, k, q, N, K);
  hipLaunchKernelGGL(attn_heads_kernel, dim3(M / 4, 1, 1), blk, 0, stream, q, k, v, ao);
  hipLaunchKernelGGL(out_gemm_kernel, dim3(N / 128, M / 128, 1), blk, 0, stream,
                     ao, Wo, bo, (float*)d_out, N, K);
}

// Round 6
// 373.764 us; speedup vs baseline: 3.3810x; 3.3810x over previous
//
#include <hip/hip_runtime.h>
#include <stdint.h>

#define EMB 1024
#define LROW 40   // staging LDS pitch (u16): 32 data + 8 pad -> 2-way max on frag reads

typedef unsigned short u16;
typedef __attribute__((ext_vector_type(8))) unsigned short u16x8;
typedef __attribute__((ext_vector_type(8))) __bf16 bf16x8;
typedef __attribute__((ext_vector_type(4))) float f32x4;

__device__ __forceinline__ u16 f2bf(float f) {
  union { float f; uint32_t u; } x; x.f = f;
  uint32_t u = x.u;
  u += 0x7fff + ((u >> 16) & 1u);   // round-to-nearest-even
  return (u16)(u >> 16);
}

// Load 8 contiguous elements (f32 -> cvt to bf16, or raw bf16) as u16x8 bits.
template<int F32>
__device__ __forceinline__ u16x8 ld8(const void* p, size_t off) {
  if (F32) {
    const float4* f = (const float4*)((const float*)p + off);
    const float4 lo = f[0], hi = f[1];
    u16x8 r;
    r[0] = f2bf(lo.x); r[1] = f2bf(lo.y); r[2] = f2bf(lo.z); r[3] = f2bf(lo.w);
    r[4] = f2bf(hi.x); r[5] = f2bf(hi.y); r[6] = f2bf(hi.z); r[7] = f2bf(hi.w);
    return r;
  }
  return *(const u16x8*)((const u16*)p + off);
}

// One 128x128 C tile of C = X @ W^T + bias. W/bias always f32 external.
// X: f32 (XF32=1) or bf16. C: f32 (CF32=1) or bf16 -- scalar stores both ways
// (round-3-proven: WRITE_SIZE == exact output size, no amplification).
// NOTE: register budget is the critical constraint -- launch_bounds(256,2)
// keeps the unified VGPR+AGPR budget at 256/wave; (256,4) caused K-loop
// scratch spill -> GB-scale HBM traffic (rounds 4-5).
template<int XF32, int CF32>
__device__ __forceinline__ void gemm_core(
    const void* __restrict__ X, const float* __restrict__ W,
    const float* __restrict__ Bias, void* __restrict__ C,
    int bm, int bn, int N, int K, u16* Al, u16* Bl)
{
  const int tid  = threadIdx.x;
  const int lane = tid & 63;
  const int w    = tid >> 6;
  const int wm = w >> 1, wn = w & 1;
  const int r16 = lane & 15, quad = lane >> 4;

  // 512 8-elem segments per 128x32 tile; thread covers seg tid and tid+256.
  const int s0 = tid, s1 = tid + 256;
  const int r0 = s0 >> 2, k0o = (s0 & 3) * 8;
  const int r1 = s1 >> 2, k1o = (s1 & 3) * 8;
  const int l0 = r0 * LROW + k0o;
  const int l1 = r1 * LROW + k1o;

  const size_t xo0 = (size_t)(bm + r0) * K + k0o;
  const size_t xo1 = (size_t)(bm + r1) * K + k1o;
  const size_t wo0 = (size_t)(bn + r0) * K + k0o;
  const size_t wo1 = (size_t)(bn + r1) * K + k1o;

  f32x4 acc[4][4];
#pragma unroll
  for (int i = 0; i < 4; i++)
#pragma unroll
    for (int j = 0; j < 4; j++)
      acc[i][j] = f32x4{0.f, 0.f, 0.f, 0.f};

  // prefetch k=0 slice
  u16x8 xa = ld8<XF32>(X, xo0);
  u16x8 xb = ld8<XF32>(X, xo1);
  u16x8 wa = ld8<1>(W, wo0);
  u16x8 wb = ld8<1>(W, wo1);

  for (int k0 = 0; k0 < K; k0 += 32) {
    *(u16x8*)&Al[l0] = xa;
    *(u16x8*)&Al[l1] = xb;
    *(u16x8*)&Bl[l0] = wa;
    *(u16x8*)&Bl[l1] = wb;
    __syncthreads();

    // prefetch next K-slice (wraps on last iter -- always valid addrs)
    const int kn = (k0 + 32 < K) ? (k0 + 32) : 0;
    xa = ld8<XF32>(X, xo0 + kn);
    xb = ld8<XF32>(X, xo1 + kn);
    wa = ld8<1>(W, wo0 + kn);
    wb = ld8<1>(W, wo1 + kn);

    bf16x8 a[4], b[4];
#pragma unroll
    for (int t = 0; t < 4; t++)
      a[t] = *(const bf16x8*)&Al[(wm * 64 + t * 16 + r16) * LROW + quad * 8];
#pragma unroll
    for (int t = 0; t < 4; t++)
      b[t] = *(const bf16x8*)&Bl[(wn * 64 + t * 16 + r16) * LROW + quad * 8];

#pragma unroll
    for (int tm = 0; tm < 4; tm++)
#pragma unroll
      for (int tn = 0; tn < 4; tn++)
        acc[tm][tn] = __builtin_amdgcn_mfma_f32_16x16x32_bf16(a[tm], b[tn], acc[tm][tn], 0, 0, 0);
    __syncthreads();
  }

  // C/D layout: col = lane&15, row = quad*4 + reg  (verified m89/m91)
#pragma unroll
  for (int tn = 0; tn < 4; tn++) {
    const int col = bn + wn * 64 + tn * 16 + r16;
    const float bias = Bias[col];
#pragma unroll
    for (int tm = 0; tm < 4; tm++) {
      const int row0 = bm + wm * 64 + tm * 16 + quad * 4;
#pragma unroll
      for (int r = 0; r < 4; r++) {
        const float val = acc[tm][tn][r] + bias;
        const size_t idx = (size_t)(row0 + r) * N + col;
        if (CF32) ((float*)C)[idx] = val;
        else      ((u16*)C)[idx]   = f2bf(val);
      }
    }
  }
}

// Fused Q/K/V projections: blockIdx.z selects operand set (1536 blocks = 6/CU).
__global__ __launch_bounds__(256, 2) void qkv_gemm_kernel(
    const float* Vx, const float* Kx, const float* Qx,
    const float* Wv, const float* bv, const float* Wk, const float* bk,
    const float* Wq, const float* bq,
    u16* cv, u16* ck, u16* cq, int N, int K)
{
  __shared__ __attribute__((aligned(16))) u16 Al[128 * LROW];
  __shared__ __attribute__((aligned(16))) u16 Bl[128 * LROW];
  const float* X; const float* W; const float* B; u16* C;
  switch (blockIdx.z) {
    case 0:  X = Vx; W = Wv; B = bv; C = cv; break;
    case 1:  X = Kx; W = Wk; B = bk; C = ck; break;
    default: X = Qx; W = Wq; B = bq; C = cq; break;
  }
  gemm_core<1, 0>(X, W, B, C, blockIdx.y * 128, blockIdx.x * 128, N, K, Al, Bl);
}

__global__ __launch_bounds__(256, 2) void out_gemm_kernel(
    const u16* X, const float* W, const float* B, float* C, int N, int K)
{
  __shared__ __attribute__((aligned(16))) u16 Al[128 * LROW];
  __shared__ __attribute__((aligned(16))) u16 Bl[128 * LROW];
  gemm_core<0, 1>(X, W, B, C, blockIdx.y * 128, blockIdx.x * 128, N, K, Al, Bl);
}

// Per-token head-mixing attention: S = (Q Kt^T)/8 over 16 heads, softmax over
// g, O = S V. One wave per token; all operands bf16 internal.
// O aliases Q (each wave reads its own Q before writing its own O).
__global__ __launch_bounds__(256, 2) void attn_heads_kernel(
    const u16* Q, const u16* Km, const u16* V, u16* O)
{
  __shared__ __attribute__((aligned(16))) u16 P[4][16 * LROW];   // P zero-padded to K=32
  __shared__ __attribute__((aligned(16))) u16 VT[4][64 * LROW];  // V^T [d][g], g-cols 16..31 zeroed

  const int tid = threadIdx.x, lane = tid & 63, w = tid >> 6;
  const int r16 = lane & 15, quad = lane >> 4;
  const size_t base = ((size_t)blockIdx.x * 4 + w) * EMB;

  // Q rows (head-major, d-contiguous) are exactly A-layout; K rows are B-layout.
  const bf16x8 aq0 = *(const bf16x8*)&Q[base + r16 * 64 + quad * 8];
  const bf16x8 aq1 = *(const bf16x8*)&Q[base + r16 * 64 + 32 + quad * 8];
  const bf16x8 bk0 = *(const bf16x8*)&Km[base + r16 * 64 + quad * 8];
  const bf16x8 bk1 = *(const bf16x8*)&Km[base + r16 * 64 + 32 + quad * 8];

  // Stage this wave's V (2 KB) transposed into VT[w].
  const u16x8 v0 = *(const u16x8*)&V[base + lane * 16];
  const u16x8 v1 = *(const u16x8*)&V[base + lane * 16 + 8];
  const u16x8 z8 = {0, 0, 0, 0, 0, 0, 0, 0};
  *(u16x8*)&VT[w][lane * LROW + 16] = z8;   // zero g-cols 16..31 (row d = lane)
  *(u16x8*)&VT[w][lane * LROW + 24] = z8;
  const int g = lane >> 2, dbase = (lane & 3) * 16;
#pragma unroll
  for (int i = 0; i < 8; i++) {
    VT[w][(dbase + i) * LROW + g]     = v0[i];
    VT[w][(dbase + 8 + i) * LROW + g] = v1[i];
  }

  f32x4 s = f32x4{0.f, 0.f, 0.f, 0.f};
  s = __builtin_amdgcn_mfma_f32_16x16x32_bf16(aq0, bk0, s, 0, 0, 0);
  s = __builtin_amdgcn_mfma_f32_16x16x32_bf16(aq1, bk1, s, 0, 0, 0);
  // s[r] = S[h=quad*4+r][g=lane&15]

  float p[4];
#pragma unroll
  for (int r = 0; r < 4; r++) {
    float v = s[r] * 0.125f;             // 1/sqrt(64)
    float m = v;
#pragma unroll
    for (int d = 8; d; d >>= 1) m = fmaxf(m, __shfl_xor(m, d, 16));
    float e = __expf(v - m);
    float sum = e;
#pragma unroll
    for (int d = 8; d; d >>= 1) sum += __shfl_xor(sum, d, 16);
    p[r] = e / sum;
  }

  // P (C-layout) -> LDS [h][g], zero-padded to K=32
#pragma unroll
  for (int r = 0; r < 4; r++) {
    P[w][(quad * 4 + r) * LROW + r16]      = f2bf(p[r]);
    P[w][(quad * 4 + r) * LROW + 16 + r16] = 0;
  }
  __syncthreads();

  const bf16x8 pa = *(const bf16x8*)&P[w][r16 * LROW + quad * 8];  // A-frag of P

#pragma unroll
  for (int c = 0; c < 4; c++) {     // 4 chunks of 16 output dims
    const bf16x8 bv = *(const bf16x8*)&VT[w][(c * 16 + r16) * LROW + quad * 8];
    f32x4 o = f32x4{0.f, 0.f, 0.f, 0.f};
    o = __builtin_amdgcn_mfma_f32_16x16x32_bf16(pa, bv, o, 0, 0, 0);
#pragma unroll
    for (int r = 0; r < 4; r++)
      O[base + (size_t)(quad * 4 + r) * 64 + c * 16 + r16] = f2bf(o[r]);
  }
}

extern "C" void kernel_launch(void* const* d_in, const int* in_sizes, int n_in,
                              void* d_out, int out_size, void* d_ws, size_t ws_size,
                              hipStream_t stream)
{
  const float* values = (const float*)d_in[0];
  const float* keys   = (const float*)d_in[1];
  const float* query  = (const float*)d_in[2];
  const float* Wv = (const float*)d_in[3];
  const float* bv = (const float*)d_in[4];
  const float* Wk = (const float*)d_in[5];
  const float* bk = (const float*)d_in[6];
  const float* Wq = (const float*)d_in[7];
  const float* bq = (const float*)d_in[8];
  const float* Wo = (const float*)d_in[9];
  const float* bo = (const float*)d_in[10];

  const int M = in_sizes[0] / EMB;   // 8192 tokens
  const int N = EMB, K = EMB;

  // ws: q | k (bf16, 16 MB each). v lives as bf16 in d_out (32 MB f32 buffer;
  // dead before out-GEMM overwrites it). Attention output aliases q.
  u16* q = (u16*)d_ws;
  u16* k = q + (size_t)M * EMB;
  u16* v = (u16*)d_out;
  u16* ao = q;

  dim3 blk(256, 1, 1);
  hipLaunchKernelGGL(qkv_gemm_kernel, dim3(N / 128, M / 128, 3), blk, 0, stream,
                     values, keys, query, Wv, bv, Wk, bk, Wq, bq, v, k, q, N, K);
  hipLaunchKernelGGL(attn_heads_kernel, dim3(M / 4, 1, 1), blk, 0, stream, q, k, v, ao);
  hipLaunchKernelGGL(out_gemm_kernel, dim3(N / 128, M / 128, 1), blk, 0, stream,
                     ao, Wo, bo, (float*)d_out, N, K);
}